// Round 16
// baseline (244.815 us; speedup 1.0000x reference)
//
#include <hip/hip_runtime.h>
#include <stdint.h>

typedef unsigned short u16;
using short8 = __attribute__((ext_vector_type(8))) short;
using f32x4v = __attribute__((ext_vector_type(4))) float;

#define NROWS 65536
#define DIM   512
#define KC    1024

#define GLOBAL_AS __attribute__((address_space(1)))
#define LDS_AS    __attribute__((address_space(3)))

__device__ __forceinline__ void gload_lds16(const void* g, void* l) {
  __builtin_amdgcn_global_load_lds((const GLOBAL_AS uint32_t*)g,
                                   (LDS_AS uint32_t*)l, 16, 0, 0);
}

__device__ __forceinline__ u16 f2bf(float f) {  // RNE float->bf16 bits
  unsigned u = __float_as_uint(f);
  return (u16)((u + 0x7fffu + ((u >> 16) & 1u)) >> 16);
}

__device__ __forceinline__ void ntstore4(float* p, f32x4v v) {
  __builtin_nontemporal_store(v, (f32x4v*)p);
}

// ---- W prep: W^T as 16-code x K32 MFMA-B fragments + ||w||^2 --------------
// cg = code>>4 (16 codes, 16 KB); frag fk = K/32 (1 KB); lane l' holds
// W[cg*16 + (l'&15)][fk*32 + (l'>>4)*8 .. +8).
__global__ __launch_bounds__(256) void wprep_kernel(const float* __restrict__ W,
                                                    short8* __restrict__ WhT8,
                                                    float* __restrict__ wnorm,
                                                    int* __restrict__ counts,
                                                    double* __restrict__ sums) {
  if (blockIdx.x == 0) {
    for (int k = threadIdx.x; k < KC; k += 256) counts[k] = 0;
    if (threadIdx.x < 2) sums[threadIdx.x] = 0.0;
  }
  int code = blockIdx.x * 4 + (threadIdx.x >> 6);
  int l = threadIdx.x & 63;
  const float* wr = W + (size_t)code * DIM + l * 8;
  float4 v0 = *(const float4*)wr;
  float4 v1 = *(const float4*)(wr + 4);
  float s = v0.x * v0.x + v0.y * v0.y + v0.z * v0.z + v0.w * v0.w
          + v1.x * v1.x + v1.y * v1.y + v1.z * v1.z + v1.w * v1.w;
  short8 pk;
  pk[0] = (short)f2bf(v0.x); pk[1] = (short)f2bf(v0.y);
  pk[2] = (short)f2bf(v0.z); pk[3] = (short)f2bf(v0.w);
  pk[4] = (short)f2bf(v1.x); pk[5] = (short)f2bf(v1.y);
  pk[6] = (short)f2bf(v1.z); pk[7] = (short)f2bf(v1.w);
  // lane l covers K [8l,8l+8): fk = l>>2, k-sub = l&3 -> dest lane (l&3)*16+(code&15)
  WhT8[(size_t)(code >> 4) * 1024 + (size_t)(l >> 2) * 64 +
       (size_t)(l & 3) * 16 + (code & 15)] = pk;
#pragma unroll
  for (int off = 32; off; off >>= 1) s += __shfl_xor(s, off, 64);
  if (l == 0) wnorm[code] = s;
}

// ---- mm: m97-style 128x128 tile, K-loop 8xBK64, split-K argmin ------------
// 256 thr = 4 waves (2x2 of 64x64 wave tiles), target 3 blocks/CU (12 waves).
// grid 4096 = 512 row-strips x 8 code-blocks; bid remapped so a strip's 8
// sharers land on one XCD (A strip stays in that XCD's L2 across 8 reads).
__global__ __launch_bounds__(256, 3) void mm_kernel(
    const float* __restrict__ X, const u16* __restrict__ WhTf,
    const float* __restrict__ wnorm, unsigned* __restrict__ wsBest,
    double* __restrict__ sums, float* __restrict__ encf) {
  __shared__ __align__(16) u16 As[128 * 64];   // 16 KB, slot^=(row&7) swizzle
  __shared__ __align__(16) u16 Bs[8 * 1024];   // 16 KB, frag-linear
  __shared__ unsigned mbuf[2][64];
  __shared__ float sflt[4];
  const int t = threadIdx.x;
  const int w = t >> 6, l = t & 63;
  const int wr = w >> 1, wc = w & 1;
  // bid remap: strip's 8 code-blocks -> one XCD
  const int xcd = blockIdx.x & 7;
  const int j = blockIdx.x >> 3;
  const int cb = j & 7;
  const int strip = xcd + 8 * (j >> 3);
  const int row0 = strip * 128;

  const int row_l = t >> 1;           // A staging: row 0..127
  const int koff = (t & 1) * 32;      // K offset within BK64

  f32x4v acc[4][4] = {};
  float xpart = 0.f;

  for (int step = 0; step < 8; ++step) {
    // ---- stage A (reg path: fp32 load -> bf16 -> swizzled ds_write) ----
    const float* as_ = X + (size_t)(row0 + row_l) * DIM + step * 64 + koff;
    f32x4v av[8];
#pragma unroll
    for (int jj = 0; jj < 4; ++jj) {
      av[2 * jj] = *(const f32x4v*)(as_ + jj * 8);
      av[2 * jj + 1] = *(const f32x4v*)(as_ + jj * 8 + 4);
    }
    // ---- stage B (4 x global_load_lds, frag-ordered linear) ----
#pragma unroll
    for (int i = 0; i < 4; ++i) {
      int chunk = i * 2 + (t >> 7);
      gload_lds16(WhTf + (size_t)(cb * 8 + chunk) * 8192 + step * 1024 + (t & 127) * 8,
                  &Bs[chunk * 1024 + (t & 127) * 8]);
    }
    // ---- enc-zero NT stream (2 stores: rows [step*16,+16) of our region) ----
    {
      int erow = row0 + step * 16 + (t >> 4);
      float* ep = encf + (size_t)erow * KC + cb * 128 + (t & 15) * 8;
      const f32x4v z4 = {0.f, 0.f, 0.f, 0.f};
      ntstore4(ep, z4);
      ntstore4(ep + 4, z4);
    }
    // ---- convert + ds_write A, fused sum(x^2) (cb==0 only) ----
    if (cb == 0) {
#pragma unroll
      for (int v = 0; v < 8; ++v)
        xpart += av[v][0] * av[v][0] + av[v][1] * av[v][1] +
                 av[v][2] * av[v][2] + av[v][3] * av[v][3];
    }
#pragma unroll
    for (int jj = 0; jj < 4; ++jj) {
      short8 pk;
      pk[0] = (short)f2bf(av[2 * jj][0]); pk[1] = (short)f2bf(av[2 * jj][1]);
      pk[2] = (short)f2bf(av[2 * jj][2]); pk[3] = (short)f2bf(av[2 * jj][3]);
      pk[4] = (short)f2bf(av[2 * jj + 1][0]); pk[5] = (short)f2bf(av[2 * jj + 1][1]);
      pk[6] = (short)f2bf(av[2 * jj + 1][2]); pk[7] = (short)f2bf(av[2 * jj + 1][3]);
      int slot = (t & 1) * 4 + jj;
      *(short8*)&As[row_l * 64 + ((slot ^ (row_l & 7)) * 8)] = pk;
    }
    __syncthreads();  // A written, B DMA drained

    // ---- compute: 2 ks x (4 a-reads + 4 b-reads + 16 MFMA) ----
#pragma unroll
    for (int ks = 0; ks < 2; ++ks) {
      short8 af[4], bf[4];
#pragma unroll
      for (int m = 0; m < 4; ++m) {
        int row = wr * 64 + m * 16 + (l & 15);
        af[m] = *(const short8*)&As[row * 64 + (((ks * 4 + (l >> 4)) ^ (row & 7)) * 8)];
      }
#pragma unroll
      for (int n = 0; n < 4; ++n)
        bf[n] = *(const short8*)&Bs[(wc * 4 + n) * 1024 + ks * 512 + l * 8];
#pragma unroll
      for (int m = 0; m < 4; ++m)
#pragma unroll
        for (int n = 0; n < 4; ++n)
          acc[m][n] = __builtin_amdgcn_mfma_f32_16x16x32_bf16(af[m], bf[n], acc[m][n], 0, 0, 0);
    }
    __syncthreads();  // all waves done with As/Bs before next staging
  }

  // ---- sum(x^2) reduce (cb==0 blocks staged the strip exactly once) ----
  if (cb == 0) {
    float xs = xpart;
#pragma unroll
    for (int off = 32; off; off >>= 1) xs += __shfl_xor(xs, off, 64);
    if (l == 0) sflt[w] = xs;
  }
  // ---- scores + per-row argmin fold (u32 key22|col10), lane-16 reduce ----
  unsigned pbv[16];
#pragma unroll
  for (int m = 0; m < 4; ++m)
#pragma unroll
    for (int r = 0; r < 4; ++r) {
      unsigned pb = 0xFFFFFFFFu;
#pragma unroll
      for (int n = 0; n < 4; ++n) {
        int col = cb * 128 + wc * 64 + n * 16 + (l & 15);
        float sc = fmaf(-2.0f, acc[m][n][r], wnorm[col]);
        unsigned u_ = __float_as_uint(sc);
        unsigned key = (u_ & 0x80000000u) ? ~u_ : (u_ | 0x80000000u);
        pb = min(pb, (key & 0xFFFFFC00u) | (unsigned)col);
      }
#pragma unroll
      for (int off = 8; off; off >>= 1)
        pb = min(pb, (unsigned)__shfl_xor((int)pb, off, 16));
      pbv[m * 4 + r] = pb;
      if (wc == 1 && (l & 15) == 0)
        mbuf[wr][m * 16 + (l >> 4) * 4 + r] = pb;
    }
  __syncthreads();
  if (cb == 0 && t == 0)
    atomicAdd(&sums[0], (double)(sflt[0] + sflt[1] + sflt[2] + sflt[3]));
  if (wc == 0 && (l & 15) == 0) {
#pragma unroll
    for (int m = 0; m < 4; ++m)
#pragma unroll
      for (int r = 0; r < 4; ++r) {
        int rl = m * 16 + (l >> 4) * 4 + r;
        unsigned pb = min(pbv[m * 4 + r], mbuf[wr][rl]);
        atomicMin(&wsBest[row0 + wr * 64 + rl], pb);
      }
  }
}

// ---- post: histogram + sum of best scores ---------------------------------
__global__ __launch_bounds__(256) void post_kernel(const unsigned* __restrict__ wsBest,
                                                   int* __restrict__ counts,
                                                   double* __restrict__ sums) {
  int i = blockIdx.x * 256 + threadIdx.x;
  unsigned pb = wsBest[i];
  int k = (int)(pb & 1023u);
  atomicAdd(&counts[k], 1);
  unsigned key = (pb & 0xFFFFFC00u) | 0x200u;  // midpoint reconstruction
  unsigned uu = (key & 0x80000000u) ? (key ^ 0x80000000u) : ~key;
  double d = (double)__uint_as_float(uu);
#pragma unroll
  for (int off = 32; off; off >>= 1) d += __shfl_xor(d, off, 64);
  if ((threadIdx.x & 63) == 0) atomicAdd(&sums[1], d);
}

// ---- out: quantized gather-write + one-hot 1.0 ----------------------------
__global__ __launch_bounds__(256) void out_kernel(const float* __restrict__ W,
                                                  const unsigned* __restrict__ wsBest,
                                                  float* __restrict__ out,
                                                  float* __restrict__ encf) {
  const int t = threadIdx.x;
  const int w = t >> 6, l = t & 63;
#pragma unroll
  for (int j = 0; j < 8; ++j) {
    int rr = blockIdx.x * 32 + w * 8 + j;
    int k = (int)(wsBest[rr] & 1023u);
    const float* Wr = W + (size_t)k * DIM;
    size_t ob = (size_t)rr * DIM;
    {
      f32x4v cm = *(const f32x4v*)(Wr + 4 * l);
      f32x4v c1 = *(const f32x4v*)(Wr + 4 * l + 4);
      f32x4v sv = {cm[3], c1[0], c1[1], c1[2]};
      ntstore4(out + ob + 4 + 4 * l, sv);
    }
    if (l <= 62) {
      int m = l + 64;
      f32x4v dm = *(const f32x4v*)(Wr + 4 * m);
      f32x4v d1 = *(const f32x4v*)(Wr + 4 * m + 4);
      f32x4v sv = {dm[3], d1[0], d1[1], d1[2]};
      ntstore4(out + ob + 4 + 4 * m, sv);
    }
    if (l < 3) out[ob + 1 + l] = Wr[l];        // head d=0,1,2
    if (l == 3) out[ob + 512] = Wr[511];       // tail d=511
    if (l == 4) encf[(size_t)rr * KC + k] = 1.0f;  // one-hot
  }
}

// ---- finalize: loss + perplexity ------------------------------------------
__global__ __launch_bounds__(256) void finalize_kernel(
    const int* __restrict__ counts, const double* __restrict__ sums,
    float* __restrict__ out_loss, float* __restrict__ out_perp) {
  __shared__ float red[4];
  int t = threadIdx.x;
  float h = 0.f;
  for (int k = t; k < KC; k += 256) {
    float p = (float)counts[k] / (float)NROWS;
    h -= p * logf(p + 1e-10f);
  }
#pragma unroll
  for (int off = 32; off; off >>= 1) h += __shfl_xor(h, off, 64);
  if ((t & 63) == 0) red[t >> 6] = h;
  __syncthreads();
  if (t == 0) {
    float H = red[0] + red[1] + red[2] + red[3];
    *out_perp = expf(H);
    double m = (sums[0] + sums[1]) / (double)((long long)NROWS * DIM);
    *out_loss = (float)(1.25 * m);
  }
}

extern "C" void kernel_launch(void* const* d_in, const int* in_sizes, int n_in,
                              void* d_out, int out_size, void* d_ws, size_t ws_size,
                              hipStream_t stream) {
  const float* X = (const float*)d_in[0];
  const float* W = (const float*)d_in[1];
  float* out = (float*)d_out;
  char* ws = (char*)d_ws;

  float* out_loss = out;                     // [0]
  float* out_perp = out + 1 + NROWS * DIM;   // [33554433]
  float* encf     = out + 2 + NROWS * DIM;   // [33554434 ..), 16B-aligned

  short8*   WhT8   = (short8*)ws;                          // 1 MB
  float*    wnorm  = (float*)(ws + (1024u << 10));         // 4 KB
  int*      counts = (int*)(ws + (1024u << 10) + 4096);    // 4 KB
  double*   sums   = (double*)(ws + (1024u << 10) + 8192); // 16 B
  unsigned* wsBest = (unsigned*)(ws + (1024u << 10) + 12288); // 256 KB

  hipMemsetAsync(wsBest, 0xFF, NROWS * sizeof(unsigned), stream);
  wprep_kernel<<<KC / 4, 256, 0, stream>>>(W, WhT8, wnorm, counts, sums);
  mm_kernel<<<(NROWS / 128) * 8, 256, 0, stream>>>(X, (const u16*)WhT8, wnorm,
                                                   wsBest, sums, encf);
  post_kernel<<<NROWS / 256, 256, 0, stream>>>(wsBest, counts, sums);
  out_kernel<<<NROWS / 32, 256, 0, stream>>>(W, wsBest, out, encf);
  finalize_kernel<<<1, 256, 0, stream>>>(counts, sums, out_loss, out_perp);
}

// Round 17
// 186.910 us; speedup vs baseline: 1.3098x; 1.3098x over previous
//
#include <hip/hip_runtime.h>
#include <stdint.h>

typedef unsigned short u16;
using short8 = __attribute__((ext_vector_type(8))) short;
using f32x16 = __attribute__((ext_vector_type(16))) float;
using f32x4v = __attribute__((ext_vector_type(4))) float;

#define NROWS 65536
#define DIM   512
#define KC    1024

#define GLOBAL_AS __attribute__((address_space(1)))
#define LDS_AS    __attribute__((address_space(3)))

__device__ __forceinline__ void gload_lds16(const void* g, void* l) {
  __builtin_amdgcn_global_load_lds((const GLOBAL_AS uint32_t*)g,
                                   (LDS_AS uint32_t*)l, 16, 0, 0);
}

__device__ __forceinline__ u16 f2bf(float f) {  // RNE float->bf16 bits
  unsigned u = __float_as_uint(f);
  return (u16)((u + 0x7fffu + ((u >> 16) & 1u)) >> 16);
}

__device__ __forceinline__ f32x4v ntload4(const float* p) {
  return __builtin_nontemporal_load((const f32x4v*)p);
}
__device__ __forceinline__ void ntstore4(float* p, f32x4v v) {
  __builtin_nontemporal_store(v, (f32x4v*)p);
}

// ---- W prep: W^T fragment order [cg(32 codes)][khalf(K=256)][ks(16)] ------
// (verified in R15) frag = 1 KB: lane (h*32+r) holds W[cg*32+r][..8].
__global__ __launch_bounds__(256) void wprep_kernel(const float* __restrict__ W,
                                                    short8* __restrict__ WhT8,
                                                    float* __restrict__ wnorm,
                                                    int* __restrict__ counts,
                                                    double* __restrict__ sums) {
  if (blockIdx.x == 0) {
    for (int k = threadIdx.x; k < KC; k += 256) counts[k] = 0;
    if (threadIdx.x < 2) sums[threadIdx.x] = 0.0;
  }
  int code = blockIdx.x * 4 + (threadIdx.x >> 6);
  int l = threadIdx.x & 63;
  const float* wr = W + (size_t)code * DIM + l * 8;
  float4 v0 = *(const float4*)wr;
  float4 v1 = *(const float4*)(wr + 4);
  float s = v0.x * v0.x + v0.y * v0.y + v0.z * v0.z + v0.w * v0.w
          + v1.x * v1.x + v1.y * v1.y + v1.z * v1.z + v1.w * v1.w;
  short8 pk;
  pk[0] = (short)f2bf(v0.x); pk[1] = (short)f2bf(v0.y);
  pk[2] = (short)f2bf(v0.z); pk[3] = (short)f2bf(v0.w);
  pk[4] = (short)f2bf(v1.x); pk[5] = (short)f2bf(v1.y);
  pk[6] = (short)f2bf(v1.z); pk[7] = (short)f2bf(v1.w);
  WhT8[(size_t)(code >> 5) * 2048 + (size_t)(l >> 5) * 1024 +
       (size_t)((l >> 1) & 15) * 64 + (l & 1) * 32 + (code & 31)] = pk;
#pragma unroll
  for (int off = 32; off; off >>= 1) s += __shfl_xor(s, off, 64);
  if (l == 0) wnorm[code] = s;
}

// ---- main fused kernel: R10 loop at 4-blocks/CU granularity ---------------
// 128 thr = 2 waves x 32 rows = 64 rows/block; grid 1024 = 4 blocks/CU.
// 4 independent block schedulers per CU break the phase convoy: LDS, MFMA,
// VALU-fold and HBM streams from different blocks overlap.
// 64 LDS-tiles of (32 codes x K=256) = 16 KB, dbuf; acc persists per cg.
__global__ __launch_bounds__(128)
__attribute__((amdgpu_waves_per_eu(2, 2))) void mm_kernel(
    const float* __restrict__ X, const float* __restrict__ W,
    const u16* __restrict__ WhTf, const float* __restrict__ wnorm,
    int* __restrict__ counts, double* __restrict__ sums,
    float* __restrict__ out, float* __restrict__ encf) {
  __shared__ __align__(16) u16 BsU[2][8192];  // 2 x 16 KB
  __shared__ int rowk[64];
  __shared__ double sdbl[2];
  const int t = threadIdx.x;
  const int w = t >> 6, l = t & 63;
  const int r = l & 31, h = l >> 5;
  const int row0 = blockIdx.x * 64;

  // kick off tile 0 DMA (8 gloads/thread x 128 thr = 16 KB)
#pragma unroll
  for (int i = 0; i < 8; ++i)
    gload_lds16(WhTf + (i * 128 + t) * 8, &BsU[0][(i * 128 + t) * 8]);

  // A panel (32 rows x 512 per wave) -> regs as MFMA A-frags, sum(x^2)
  const float* Xr = X + (size_t)(row0 + w * 32 + r) * DIM + h * 8;
  short8 aF[32];
  double xacc = 0.0;
#pragma unroll
  for (int s = 0; s < 32; ++s) {
    f32x4v v0 = ntload4(Xr + s * 16);
    f32x4v v1 = ntload4(Xr + s * 16 + 4);
    xacc += (double)v0[0] * v0[0] + (double)v0[1] * v0[1] + (double)v0[2] * v0[2] + (double)v0[3] * v0[3]
          + (double)v1[0] * v1[0] + (double)v1[1] * v1[1] + (double)v1[2] * v1[2] + (double)v1[3] * v1[3];
    short8 pk;
    pk[0] = (short)f2bf(v0[0]); pk[1] = (short)f2bf(v0[1]);
    pk[2] = (short)f2bf(v0[2]); pk[3] = (short)f2bf(v0[3]);
    pk[4] = (short)f2bf(v1[0]); pk[5] = (short)f2bf(v1[1]);
    pk[6] = (short)f2bf(v1[2]); pk[7] = (short)f2bf(v1[3]);
    aF[s] = pk;
  }
#pragma unroll
  for (int off = 32; off; off >>= 1) xacc += __shfl_xor(xacc, off, 64);
  if (l == 0) atomicAdd(&sums[0], xacc);

  unsigned best_[16];
#pragma unroll
  for (int q = 0; q < 16; ++q) best_[q] = 0xFFFFFFFFu;

  f32x4v* encz = (f32x4v*)(encf + (size_t)row0 * KC);
  const f32x4v zero4 = {0.f, 0.f, 0.f, 0.f};

  asm volatile("s_waitcnt vmcnt(0)" ::: "memory");  // tile 0 resident
  __builtin_amdgcn_s_barrier();
  __builtin_amdgcn_sched_barrier(0);

  for (int cg = 0; cg < 32; ++cg) {
    f32x16 acc_e = {}, acc_o = {};
#pragma unroll
    for (int khalf = 0; khalf < 2; ++khalf) {
      const int kt = cg * 2 + khalf;
      const int buf = kt & 1;
      if (kt < 63) {  // prefetch next tile FIRST (8 gloads = oldest)
        const u16* src = WhTf + (size_t)(kt + 1) * 8192;
#pragma unroll
        for (int i = 0; i < 8; ++i)
          gload_lds16(src + (i * 128 + t) * 8, &BsU[buf ^ 1][(i * 128 + t) * 8]);
      }
      // enc-zero NT stream (2 stores = newest; ride with slack)
#pragma unroll
      for (int j = 0; j < 2; ++j)
        __builtin_nontemporal_store(zero4, &encz[kt * 256 + j * 128 + t]);

      const u16* bufp = &BsU[buf][l * 8];
#pragma unroll
      for (int ks = 0; ks < 16; ++ks) {
        short8 bv = *(const short8*)&bufp[ks * 512];
        if (ks & 1)
          acc_o = __builtin_amdgcn_mfma_f32_32x32x16_bf16(aF[khalf * 16 + ks], bv, acc_o, 0, 0, 0);
        else
          acc_e = __builtin_amdgcn_mfma_f32_32x32x16_bf16(aF[khalf * 16 + ks], bv, acc_e, 0, 0, 0);
      }
      if (khalf) {
        float wn = wnorm[cg * 32 + r];
        unsigned col = (unsigned)(cg * 32 + r);
#pragma unroll
        for (int q = 0; q < 16; ++q) {
          float sc = fmaf(-2.0f, acc_e[q] + acc_o[q], wn);
          unsigned u_ = __float_as_uint(sc);
          unsigned key = (u_ & 0x80000000u) ? ~u_ : (u_ | 0x80000000u);
          best_[q] = min(best_[q], (key & 0xFFFFFC00u) | col);
        }
      }
      // drain this phase's 8 gloads; leave our 2 NT stores in flight
      asm volatile("s_waitcnt vmcnt(2)" ::: "memory");
      __builtin_amdgcn_s_barrier();
      __builtin_amdgcn_sched_barrier(0);
    }
  }

  // per-row argmin across the 32 code-lanes; rowk + stats
  double local = 0.0;
#pragma unroll
  for (int q = 0; q < 16; ++q) {
    unsigned pb = best_[q];
#pragma unroll
    for (int off = 16; off; off >>= 1)
      pb = min(pb, (unsigned)__shfl_xor((int)pb, off, 32));
    if (r == 0) {
      int rit = w * 32 + (q & 3) + 8 * (q >> 2) + 4 * h;
      int k = (int)(pb & 1023u);
      rowk[rit] = k;
      atomicAdd(&counts[k], 1);
      unsigned key = (pb & 0xFFFFFC00u) | 0x200u;  // midpoint reconstruction
      unsigned uu = (key & 0x80000000u) ? (key ^ 0x80000000u) : ~key;
      local += (double)__uint_as_float(uu);
    }
  }
  {
    double o32 = __shfl(local, 32, 64);
    if (l == 0) sdbl[w] = local + o32;
  }
  __syncthreads();  // full drain: zeros committed before 1.0 scatter
  if (t == 0) atomicAdd(&sums[1], sdbl[0] + sdbl[1]);

  // fused quantized gather-write (aligned f4 NT around +1 base) + one-hot
  for (int j = 0; j < 32; ++j) {
    int rit = w * 32 + j;
    int k = rowk[rit];
    const float* Wr = W + (size_t)k * DIM;
    size_t ob = (size_t)(row0 + rit) * DIM;
    {
      f32x4v cm = *(const f32x4v*)(Wr + 4 * l);
      f32x4v c1 = *(const f32x4v*)(Wr + 4 * l + 4);
      f32x4v sv = {cm[3], c1[0], c1[1], c1[2]};
      ntstore4(out + ob + 4 + 4 * l, sv);
    }
    if (l <= 62) {
      int m = l + 64;
      f32x4v dm = *(const f32x4v*)(Wr + 4 * m);
      f32x4v d1 = *(const f32x4v*)(Wr + 4 * m + 4);
      f32x4v sv = {dm[3], d1[0], d1[1], d1[2]};
      ntstore4(out + ob + 4 + 4 * m, sv);
    }
    if (l < 3) out[ob + 1 + l] = Wr[l];        // head d=0,1,2
    if (l == 3) out[ob + 512] = Wr[511];       // tail d=511
    if (l == 4) encf[(size_t)(row0 + rit) * KC + k] = 1.0f;  // one-hot
  }
}

// ---- finalize: loss + perplexity ------------------------------------------
__global__ __launch_bounds__(256) void finalize_kernel(
    const int* __restrict__ counts, const double* __restrict__ sums,
    float* __restrict__ out_loss, float* __restrict__ out_perp) {
  __shared__ float red[4];
  int t = threadIdx.x;
  float h = 0.f;
  for (int k = t; k < KC; k += 256) {
    float p = (float)counts[k] / (float)NROWS;
    h -= p * logf(p + 1e-10f);
  }
#pragma unroll
  for (int off = 32; off; off >>= 1) h += __shfl_xor(h, off, 64);
  if ((t & 63) == 0) red[t >> 6] = h;
  __syncthreads();
  if (t == 0) {
    float H = red[0] + red[1] + red[2] + red[3];
    *out_perp = expf(H);
    double m = (sums[0] + sums[1]) / (double)((long long)NROWS * DIM);
    *out_loss = (float)(1.25 * m);
  }
}

extern "C" void kernel_launch(void* const* d_in, const int* in_sizes, int n_in,
                              void* d_out, int out_size, void* d_ws, size_t ws_size,
                              hipStream_t stream) {
  const float* X = (const float*)d_in[0];
  const float* W = (const float*)d_in[1];
  float* out = (float*)d_out;
  char* ws = (char*)d_ws;

  float* out_loss = out;                     // [0]
  float* out_perp = out + 1 + NROWS * DIM;   // [33554433]
  float* encf     = out + 2 + NROWS * DIM;   // [33554434 ..), 16B-aligned

  short8* WhT8   = (short8*)ws;                        // 1 MB
  float*  wnorm  = (float*)(ws + (1040u << 10));       // 4 KB
  int*    counts = (int*)(ws + (1040u << 10) + 4096);  // 4 KB
  double* sums   = (double*)(ws + (1040u << 10) + 8192); // [0]=sumX2 [1]=sumS

  wprep_kernel<<<KC / 4, 256, 0, stream>>>(W, WhT8, wnorm, counts, sums);
  mm_kernel<<<NROWS / 64, 128, 0, stream>>>(X, W, (const u16*)WhT8, wnorm,
                                            counts, sums, out, encf);
  finalize_kernel<<<1, 256, 0, stream>>>(counts, sums, out_loss, out_perp);
}